// Round 20
// baseline (171.987 us; speedup 1.0000x reference)
//
#include <hip/hip_runtime.h>
#include <hip/hip_bf16.h>
#include <cmath>

#define LNEPS 1e-5f

typedef __attribute__((ext_vector_type(8))) short short8v;
typedef __attribute__((ext_vector_type(4))) float f32x4;

__device__ __forceinline__ unsigned short f2bf(float f){
  unsigned u = __float_as_uint(f);
  u += 0x7fffu + ((u >> 16) & 1u);
  return (unsigned short)(u >> 16);
}
__device__ __forceinline__ float gelu_f(float x){
  return 0.5f * x * (1.f + erff(x * 0.70710678118654752f));   // exact; used for LUT build
}
template <int P>
__device__ __forceinline__ void setprio(){
#ifdef __HIP_DEVICE_COMPILE__
  __builtin_amdgcn_s_setprio(P);
#endif
}

__device__ __forceinline__ f32x4 mfma32(short8v a, short8v b, f32x4 c){
#ifdef __HIP_DEVICE_COMPILE__
  return __builtin_amdgcn_mfma_f32_16x16x32_bf16(a, b, c, 0, 0, 0);
#else
  return c;
#endif
}

// Stage 128x128 bf16 -> LDS via global_load_lds, 256 threads (8 iters).
__device__ __forceinline__ void stage128(const unsigned short* g, int ldg, short* lds){
#ifdef __HIP_DEVICE_COMPILE__
  const int t = threadIdx.x;
  const int wv = t >> 6;
  #pragma unroll
  for (int it = 0; it < 8; ++it) {
    const int flat = it * 256 + t;
    const int r = flat >> 4, c = flat & 15;
    const unsigned short* src = g + (size_t)r * ldg + ((c ^ (r & 7)) << 3);
    short* dst = lds + (size_t)(it * 256 + wv * 64) * 8;
    __builtin_amdgcn_global_load_lds(
        (const __attribute__((address_space(1))) void*)src,
        (__attribute__((address_space(3))) void*)dst, 16, 0, 0);
  }
#else
  (void)g; (void)ldg; (void)lds;
#endif
}
// Stage 64x128 bf16 (256 threads).
__device__ __forceinline__ void stage64(const unsigned short* g, short* lds){
#ifdef __HIP_DEVICE_COMPILE__
  const int t = threadIdx.x;
  const int wv = t >> 6;
  #pragma unroll
  for (int it = 0; it < 4; ++it) {
    const int flat = it * 256 + t;
    const int r = flat >> 4, c = flat & 15;
    const unsigned short* src = g + (size_t)r * 128 + ((c ^ (r & 7)) << 3);
    short* dst = lds + (size_t)(it * 256 + wv * 64) * 8;
    __builtin_amdgcn_global_load_lds(
        (const __attribute__((address_space(1))) void*)src,
        (__attribute__((address_space(3))) void*)dst, 16, 0, 0);
  }
#else
  (void)g; (void)lds;
#endif
}
// Swizzled 16B fragment read: row-major [row][128 bf16] (256B rows).
__device__ __forceinline__ short8v frag_ld(const short* lds, int row, int chunk){
  return *(const short8v*)((const char*)lds + row * 256 + ((chunk ^ (row & 7)) << 4));
}

// ---------------- K0: weights f32 -> bf16, plus bias-table expansion (merged k0b) ----------------
__global__ __launch_bounds__(256) void k0_cvt(
    const float* __restrict__ qkvw, const float* __restrict__ pw,
    const float* __restrict__ w1, const float* __restrict__ w2,
    const float* __restrict__ table,
    unsigned short* __restrict__ dst, float* __restrict__ be)
{
  if (blockIdx.x < 192) {
    const int i = (blockIdx.x * 256 + threadIdx.x) * 4;
    const float* src; int off;
    if (i < 49152)       { src = qkvw; off = i; }
    else if (i < 65536)  { src = pw;   off = i - 49152; }
    else if (i < 131072) { src = w1;   off = i - 65536; }
    else                 { src = w2;   off = i - 131072; }
    const float4 v = *(const float4*)(src + off);
    ushort4 o = { f2bf(v.x), f2bf(v.y), f2bf(v.z), f2bf(v.w) };
    *(ushort4*)(dst + i) = o;
  } else {
    const int i = (blockIdx.x - 192) * 256 + threadIdx.x;   // 8192 float4 slots
    const int m4 = (i & 15) * 4;
    const int r  = (i >> 4) & 63;
    const int h  = i >> 10;
    const int i1 = r >> 3, j1 = r & 7;
    float o[4];
    #pragma unroll
    for (int e = 0; e < 4; ++e) {
      const int m = m4 + e;
      const int i2 = m >> 3, j2 = m & 7;
      o[e] = table[((i1 - i2 + 7) * 15 + (j1 - j2 + 7)) * 8 + h];
    }
    float4 ov = { o[0], o[1], o[2], o[3] };
    *(float4*)(be + ((h * 64 + r) * 64 + m4)) = ov;
  }
}

// ---------------- K23: fused LN1+shift+window + qkv GEMM + window attention ----------------
// One window per 256-thread block; LDS = 80 KB -> 2 blocks/CU. r20: T14 reorder --
// weight stage issued BEFORE the QK-write so its latency hides under the write.
__global__ __launch_bounds__(256, 2) void k23_qkv_attn(
    const float* __restrict__ x,
    const float* __restrict__ gw, const float* __restrict__ gb,
    const unsigned short* __restrict__ Wb,
    const float* __restrict__ bias,
    const float* __restrict__ be,          // expanded bias [8][64][64] f32
    unsigned short* __restrict__ attn)
{
  __shared__ __align__(16) short At[128 * 128];   // 32K: weight tile; later P (4K/wave)
  __shared__ __align__(16) short Bt[64 * 128];    // 16K: ln1(x); later V^T [8][16][64]
  __shared__ __align__(16) short QK[64 * 256];    // 32K: Q|K (512B rows, swizzled)
  const int t = threadIdx.x;
  const int win = blockIdx.x;
  const int row0 = win * 64;
  stage128(Wb, 128, At);                          // Wq tile, async under LN
  // ---- LN1 + shift + window partition -> Bt (16 threads/row, 64 rows) ----
  #pragma unroll
  for (int it = 0; it < 4; ++it) {
    const int flat = it * 256 + t;
    const int r = flat >> 4, c = flat & 15;
    const int row = row0 + r;
    const int wid = row >> 6, n = row & 63;
    const int b = wid >> 10, rem = wid & 1023;
    const int wh = rem >> 5, wwi = rem & 31;
    const int i2 = n >> 3, j2 = n & 7;
    const int sh = (wh * 8 + i2 + 4) & 255;
    const int sw = (wwi * 8 + j2 + 4) & 255;
    const float* src = x + (((size_t)b << 16) + sh * 256 + sw) * 128 + c * 8;
    const float4 a0 = *(const float4*)src;
    const float4 a1 = *(const float4*)(src + 4);
    float s  = a0.x + a0.y + a0.z + a0.w + a1.x + a1.y + a1.z + a1.w;
    float ss = a0.x*a0.x + a0.y*a0.y + a0.z*a0.z + a0.w*a0.w
             + a1.x*a1.x + a1.y*a1.y + a1.z*a1.z + a1.w*a1.w;
    s += __shfl_xor(s, 1); ss += __shfl_xor(ss, 1);
    s += __shfl_xor(s, 2); ss += __shfl_xor(ss, 2);
    s += __shfl_xor(s, 4); ss += __shfl_xor(ss, 4);
    s += __shfl_xor(s, 8); ss += __shfl_xor(ss, 8);
    const float mean = s * 0.0078125f;
    const float rstd = rsqrtf(ss * 0.0078125f - mean * mean + LNEPS);
    const float4 g0 = *(const float4*)(gw + c * 8), g1 = *(const float4*)(gw + c * 8 + 4);
    const float4 c0 = *(const float4*)(gb + c * 8), c1 = *(const float4*)(gb + c * 8 + 4);
    uint4 pk;
    pk.x = (unsigned)f2bf((a0.x - mean) * rstd * g0.x + c0.x)
         | ((unsigned)f2bf((a0.y - mean) * rstd * g0.y + c0.y) << 16);
    pk.y = (unsigned)f2bf((a0.z - mean) * rstd * g0.z + c0.z)
         | ((unsigned)f2bf((a0.w - mean) * rstd * g0.w + c0.w) << 16);
    pk.z = (unsigned)f2bf((a1.x - mean) * rstd * g1.x + c1.x)
         | ((unsigned)f2bf((a1.y - mean) * rstd * g1.y + c1.y) << 16);
    pk.w = (unsigned)f2bf((a1.z - mean) * rstd * g1.z + c1.z)
         | ((unsigned)f2bf((a1.w - mean) * rstd * g1.w + c1.w) << 16);
    *(uint4*)((char*)Bt + r * 256 + ((c ^ (r & 7)) << 4)) = pk;
  }
  __syncthreads();

  const int l = t & 63, w = t >> 6, w0 = w & 1, w1 = w >> 1;   // 4 waves: 2 col x 2 row
  const int g = l >> 4, rl = l & 15;
  const f32x4 z = {0.f, 0.f, 0.f, 0.f};

  // ---- qkv GEMM: Q|K -> QK, V -> V^T in Bt ----
  for (int nt = 0; nt < 3; ++nt) {
    f32x4 acc[4][2];
    #pragma unroll
    for (int i = 0; i < 4; ++i) { acc[i][0] = z; acc[i][1] = z; }
    #pragma unroll
    for (int kk = 0; kk < 4; ++kk) {
      short8v a[4], b[2];
      #pragma unroll
      for (int i = 0; i < 4; ++i) a[i] = frag_ld(At, w0 * 64 + i * 16 + rl, kk * 4 + g);
      #pragma unroll
      for (int j = 0; j < 2; ++j) b[j] = frag_ld(Bt, w1 * 32 + j * 16 + rl, kk * 4 + g);
      #pragma unroll
      for (int i = 0; i < 4; ++i)
        #pragma unroll
        for (int j = 0; j < 2; ++j)
          acc[i][j] = mfma32(a[i], b[j], acc[i][j]);
    }
    if (nt < 2) {
      __syncthreads();                            // At reads done block-wide
      stage128(Wb + (size_t)(nt + 1) * 16384, 128, At);   // T14: issue next tile
      #pragma unroll
      for (int i = 0; i < 4; ++i) {               // QK-write covers stage latency
        const int c = w0 * 64 + i * 16 + 4 * g;
        const float4 bv = *(const float4*)(bias + nt * 128 + c);
        const int chunk = nt * 16 + (c >> 3), inner = (c & 7) * 2;
        #pragma unroll
        for (int j = 0; j < 2; ++j) {
          const int r = w1 * 32 + j * 16 + rl;
          ushort4 o = { f2bf(acc[i][j][0] + bv.x), f2bf(acc[i][j][1] + bv.y),
                        f2bf(acc[i][j][2] + bv.z), f2bf(acc[i][j][3] + bv.w) };
          *(ushort4*)((char*)QK + r * 512 + ((chunk ^ (r & 7)) << 4) + inner) = o;
        }
      }
      __syncthreads();                            // next weight tile + QK writes ready
    } else {
      __syncthreads();                            // all At/Bt reads done -> Bt reusable
      #pragma unroll
      for (int i = 0; i < 4; ++i) {
        const int c = w0 * 64 + i * 16 + 4 * g;
        const int h2 = c >> 4, db = c & 15;
        const float4 bv = *(const float4*)(bias + 256 + c);
        const float ba[4] = {bv.x, bv.y, bv.z, bv.w};
        #pragma unroll
        for (int j = 0; j < 2; ++j) {
          const int m = w1 * 32 + j * 16 + rl;    // token index in window
          char* vb = (char*)Bt + h2 * 2048;
          #pragma unroll
          for (int e = 0; e < 4; ++e) {
            const int d = db + e;
            *(unsigned short*)(vb + d * 128 + (((m >> 3) ^ (d & 7)) << 4) + (m & 7) * 2)
                = f2bf(acc[i][j][e] + ba[e]);
          }
        }
      }
      __syncthreads();                            // V^T visible
    }
  }

  // ---- attention: 4 waves x 2 heads each ----
  char* Pw = (char*)At + w * 4096;
  const short8v zz = {0,0,0,0,0,0,0,0};
  for (int hh = 0; hh < 2; ++hh) {
    const int h = w * 2 + hh;
    short8v qf[4], kf[4];
    if (g < 2) {
      #pragma unroll
      for (int rf = 0; rf < 4; ++rf) {
        const int r = rf * 16 + rl;
        qf[rf] = *(const short8v*)((char*)QK + r * 512 + (((2 * h + g) ^ (r & 7)) << 4));
      }
      #pragma unroll
      for (int mf = 0; mf < 4; ++mf) {
        const int r = mf * 16 + rl;
        kf[mf] = *(const short8v*)((char*)QK + r * 512 + (((16 + 2 * h + g) ^ (r & 7)) << 4));
      }
    } else {
      #pragma unroll
      for (int i = 0; i < 4; ++i) { qf[i] = zz; kf[i] = zz; }
    }
    f32x4 s[4][4];
    #pragma unroll
    for (int mf = 0; mf < 4; ++mf)
      #pragma unroll
      for (int rf = 0; rf < 4; ++rf)
        s[mf][rf] = mfma32(kf[mf], qf[rf], z);    // S^T: m = mf*16+4g+e, r = rf*16+rl
    float sum[4];
    #pragma unroll
    for (int rf = 0; rf < 4; ++rf) {
      const int r = rf * 16 + rl;
      const float* bp = be + (size_t)(h * 64 + r) * 64;
      float mx = -1e30f;
      #pragma unroll
      for (int mf = 0; mf < 4; ++mf) {
        const float4 bv = *(const float4*)(bp + mf * 16 + g * 4);
        const float ba[4] = {bv.x, bv.y, bv.z, bv.w};
        #pragma unroll
        for (int e = 0; e < 4; ++e) {
          const float v = s[mf][rf][e] * 0.25f + ba[e];
          s[mf][rf][e] = v;
          mx = fmaxf(mx, v);
        }
      }
      mx = fmaxf(mx, __shfl_xor(mx, 16));
      mx = fmaxf(mx, __shfl_xor(mx, 32));
      float sm = 0.f;
      #pragma unroll
      for (int mf = 0; mf < 4; ++mf)
        #pragma unroll
        for (int e = 0; e < 4; ++e) {
          const float ev = __expf(s[mf][rf][e] - mx);
          s[mf][rf][e] = ev;
          sm += ev;
        }
      sm += __shfl_xor(sm, 16);
      sm += __shfl_xor(sm, 32);
      sum[rf] = sm;
    }
    // PV in two m-halves through the per-wave P buffer (intra-wave ordering).
    const char* vbase = (char*)Bt + h * 2048;
    f32x4 o[4];
    #pragma unroll
    for (int rf = 0; rf < 4; ++rf) o[rf] = z;
    #pragma unroll
    for (int hm = 0; hm < 2; ++hm) {
      #pragma unroll
      for (int rf = 0; rf < 4; ++rf) {
        const int r = rf * 16 + rl;
        #pragma unroll
        for (int mfl = 0; mfl < 2; ++mfl) {
          const int mf = hm * 2 + mfl;
          uint2 u;
          u.x = (unsigned)f2bf(s[mf][rf][0]) | ((unsigned)f2bf(s[mf][rf][1]) << 16);
          u.y = (unsigned)f2bf(s[mf][rf][2]) | ((unsigned)f2bf(s[mf][rf][3]) << 16);
          *(uint2*)(Pw + r * 64 + (((mfl * 2 + (g >> 1)) ^ ((r >> 1) & 3)) << 4) + (g & 1) * 8) = u;
        }
      }
      const short8v va = *(const short8v*)(vbase + rl * 128 + (((hm * 4 + g) ^ (rl & 7)) << 4));
      #pragma unroll
      for (int rf = 0; rf < 4; ++rf) {
        const int r = rf * 16 + rl;
        const short8v pb = *(const short8v*)(Pw + r * 64 + ((g ^ ((r >> 1) & 3)) << 4));
        o[rf] = mfma32(va, pb, o[rf]);
      }
    }
    #pragma unroll
    for (int rf = 0; rf < 4; ++rf) {
      const float inv = 1.f / sum[rf];
      const int r = rf * 16 + rl;
      ushort4 ov = { f2bf(o[rf][0] * inv), f2bf(o[rf][1] * inv),
                     f2bf(o[rf][2] * inv), f2bf(o[rf][3] * inv) };
      *(ushort4*)(attn + ((size_t)win * 64 + r) * 128 + h * 16 + g * 4) = ov;
    }
  }
}

// ---------------- K45: fused proj + unshift-residual + LN2 + fc1 + GELU + fc2 + residual ----------------
// r18-proven core; r20: stage(W1[0]) issued after the Red-barrier (hides under LN2
// finish + Xt write); loop sb=0 needs only one barrier.
__global__ __launch_bounds__(256, 2) void k45_proj_mlp(
    const unsigned short* __restrict__ A,
    const unsigned short* __restrict__ pwb,
    const float* __restrict__ pb,
    const float* __restrict__ xin,
    const float* __restrict__ gw, const float* __restrict__ gb,
    const unsigned short* __restrict__ w1b, const float* __restrict__ b1,
    const unsigned short* __restrict__ w2b, const float* __restrict__ b2,
    float* __restrict__ out)
{
  __shared__ __align__(16) short Xt[64 * 128];
  __shared__ __align__(16) short Ht[64 * 128];
  __shared__ __align__(16) short Wt[128 * 128];
  __shared__ float2 Gt[1024];
  __shared__ float2 Red[64 * 8];
  const int t = threadIdx.x;
  const int row0 = blockIdx.x * 64;
  stage128(pwb, 128, Wt);
  stage64(A + (size_t)row0 * 128, Ht);
  #pragma unroll
  for (int i = t; i < 1024; i += 256) {
    const float x0 = (float)i * 0.0078125f - 4.f;
    const float g0 = gelu_f(x0);
    Gt[i] = make_float2(g0, gelu_f(x0 + 0.0078125f) - g0);
  }
  const int l = t & 63, w = t >> 6, w0 = w & 1, w1 = w >> 1;
  const int g = l >> 4, rl = l & 15;
  size_t obase[2];
  float4 xv[4][2];
  #pragma unroll
  for (int j = 0; j < 2; ++j) {
    const int r = row0 + w1 * 32 + j * 16 + rl;
    const int wn = r >> 6, n = r & 63;
    const int b_ = wn >> 10, rem = wn & 1023;
    const int wh = rem >> 5, ww = rem & 31;
    const int si = n >> 3, sj = n & 7;
    const int hd = (wh * 8 + si + 4) & 255;
    const int wd = (ww * 8 + sj + 4) & 255;
    obase[j] = (((size_t)b_ << 16) + hd * 256 + wd) * 128;
    #pragma unroll
    for (int i = 0; i < 4; ++i)
      xv[i][j] = *(const float4*)(xin + obase[j] + w0 * 64 + i * 16 + 4 * g);
  }
  __syncthreads();
  const f32x4 z = {0.f, 0.f, 0.f, 0.f};
  f32x4 x2r[4][2];
  #pragma unroll
  for (int i = 0; i < 4; ++i) { x2r[i][0] = z; x2r[i][1] = z; }
  setprio<1>();
  #pragma unroll
  for (int kk = 0; kk < 4; ++kk) {
    short8v a[4], b[2];
    #pragma unroll
    for (int i = 0; i < 4; ++i) a[i] = frag_ld(Wt, w0 * 64 + i * 16 + rl, kk * 4 + g);
    #pragma unroll
    for (int j = 0; j < 2; ++j) b[j] = frag_ld(Ht, w1 * 32 + j * 16 + rl, kk * 4 + g);
    #pragma unroll
    for (int i = 0; i < 4; ++i)
      #pragma unroll
      for (int j = 0; j < 2; ++j)
        x2r[i][j] = mfma32(a[i], b[j], x2r[i][j]);
  }
  setprio<0>();
  #pragma unroll
  for (int i = 0; i < 4; ++i) {
    const float4 bv = *(const float4*)(pb + w0 * 64 + i * 16 + 4 * g);
    #pragma unroll
    for (int j = 0; j < 2; ++j) {
      x2r[i][j][0] += xv[i][j].x + bv.x;
      x2r[i][j][1] += xv[i][j].y + bv.y;
      x2r[i][j][2] += xv[i][j].z + bv.z;
      x2r[i][j][3] += xv[i][j].w + bv.w;
    }
  }
  #pragma unroll
  for (int j = 0; j < 2; ++j) {
    float s = 0.f, ss = 0.f;
    #pragma unroll
    for (int i = 0; i < 4; ++i)
      #pragma unroll
      for (int e = 0; e < 4; ++e) { const float v = x2r[i][j][e]; s += v; ss += v * v; }
    Red[(w1 * 32 + j * 16 + rl) * 8 + (w0 * 4 + g)] = make_float2(s, ss);
  }
  __syncthreads();                         // Red ready AND all proj Wt reads done
  stage128(w1b, 128, Wt);                  // T14: W1[0] hides under LN2 finish + Xt write
  float mean[2], rstd[2];
  #pragma unroll
  for (int j = 0; j < 2; ++j) {
    const float2* rp = &Red[(w1 * 32 + j * 16 + rl) * 8];
    float s = 0.f, ss = 0.f;
    #pragma unroll
    for (int k = 0; k < 8; ++k) { s += rp[k].x; ss += rp[k].y; }
    mean[j] = s * 0.0078125f;
    rstd[j] = rsqrtf(ss * 0.0078125f - mean[j] * mean[j] + LNEPS);
  }
  #pragma unroll
  for (int i = 0; i < 4; ++i) {
    const int c = w0 * 64 + i * 16 + 4 * g;
    const float4 g4 = *(const float4*)(gw + c);
    const float4 c4 = *(const float4*)(gb + c);
    #pragma unroll
    for (int j = 0; j < 2; ++j) {
      const int r = w1 * 32 + j * 16 + rl;
      ushort4 p;
      p.x = f2bf((x2r[i][j][0] - mean[j]) * rstd[j] * g4.x + c4.x);
      p.y = f2bf((x2r[i][j][1] - mean[j]) * rstd[j] * g4.y + c4.y);
      p.z = f2bf((x2r[i][j][2] - mean[j]) * rstd[j] * g4.z + c4.z);
      p.w = f2bf((x2r[i][j][3] - mean[j]) * rstd[j] * g4.w + c4.w);
      const int chunk = c >> 3, inner = (c & 7) * 2;
      *(ushort4*)((char*)Xt + r * 256 + ((chunk ^ (r & 7)) << 4) + inner) = p;
    }
  }
  f32x4 oacc[4][2];
  #pragma unroll
  for (int i = 0; i < 4; ++i) { oacc[i][0] = z; oacc[i][1] = z; }
  for (int sb = 0; sb < 4; ++sb) {
    __syncthreads();                       // sb=0: Xt + W1[0] ready; sb>0: prev Wt/Ht reads done
    if (sb > 0) {
      stage128(w1b + (size_t)sb * 16384, 128, Wt);
      __syncthreads();                     // W1[sb] ready
    }
    f32x4 hacc[4][2];
    #pragma unroll
    for (int i = 0; i < 4; ++i) { hacc[i][0] = z; hacc[i][1] = z; }
    setprio<1>();
    #pragma unroll
    for (int kk = 0; kk < 4; ++kk) {
      short8v a[4], b[2];
      #pragma unroll
      for (int i = 0; i < 4; ++i) a[i] = frag_ld(Wt, w0 * 64 + i * 16 + rl, kk * 4 + g);
      #pragma unroll
      for (int j = 0; j < 2; ++j) b[j] = frag_ld(Xt, w1 * 32 + j * 16 + rl, kk * 4 + g);
      #pragma unroll
      for (int i = 0; i < 4; ++i)
        #pragma unroll
        for (int j = 0; j < 2; ++j)
          hacc[i][j] = mfma32(a[i], b[j], hacc[i][j]);
    }
    setprio<0>();
    __syncthreads();                       // fc1 done reading Wt
    stage128(w2b + (size_t)sb * 128, 512, Wt);   // T14: W2 issued BEFORE GELU
    #pragma unroll
    for (int i = 0; i < 4; ++i) {
      const int cl = w0 * 64 + i * 16 + 4 * g;
      const float4 b1v = *(const float4*)(b1 + sb * 128 + cl);
      const float ba[4] = {b1v.x, b1v.y, b1v.z, b1v.w};
      #pragma unroll
      for (int j = 0; j < 2; ++j) {
        const int r = w1 * 32 + j * 16 + rl;
        unsigned short pe[4];
        #pragma unroll
        for (int e = 0; e < 4; ++e) {
          const float xh = hacc[i][j][e] + ba[e];
          float tq = fmaf(xh, 128.f, 512.f);
          tq = fminf(fmaxf(tq, 0.f), 1023.99f);
          const float fi = floorf(tq);
          const float2 ent = Gt[(int)fi];
          float gv = fmaf(tq - fi, ent.y, ent.x);
          gv = xh > 3.98f ? xh : gv;
          pe[e] = f2bf(gv);
        }
        ushort4 p = { pe[0], pe[1], pe[2], pe[3] };
        const int chunk = cl >> 3, inner = (cl & 7) * 2;
        *(ushort4*)((char*)Ht + r * 256 + ((chunk ^ (r & 7)) << 4) + inner) = p;
      }
    }
    __syncthreads();                       // W2 + Ht ready
    setprio<1>();
    #pragma unroll
    for (int kk = 0; kk < 4; ++kk) {
      short8v a[4], b[2];
      #pragma unroll
      for (int i = 0; i < 4; ++i) a[i] = frag_ld(Wt, w0 * 64 + i * 16 + rl, kk * 4 + g);
      #pragma unroll
      for (int j = 0; j < 2; ++j) b[j] = frag_ld(Ht, w1 * 32 + j * 16 + rl, kk * 4 + g);
      #pragma unroll
      for (int i = 0; i < 4; ++i)
        #pragma unroll
        for (int j = 0; j < 2; ++j)
          oacc[i][j] = mfma32(a[i], b[j], oacc[i][j]);
    }
    setprio<0>();
  }
  #pragma unroll
  for (int i = 0; i < 4; ++i) {
    const int c = w0 * 64 + i * 16 + 4 * g;
    const float4 bv = *(const float4*)(b2 + c);
    #pragma unroll
    for (int j = 0; j < 2; ++j) {
      float4 o = { x2r[i][j][0] + oacc[i][j][0] + bv.x,
                   x2r[i][j][1] + oacc[i][j][1] + bv.y,
                   x2r[i][j][2] + oacc[i][j][2] + bv.z,
                   x2r[i][j][3] + oacc[i][j][3] + bv.w };
      *(float4*)(out + obase[j] + c) = o;
    }
  }
}

extern "C" void kernel_launch(void* const* d_in, const int* in_sizes, int n_in,
                              void* d_out, int out_size, void* d_ws, size_t ws_size,
                              hipStream_t stream)
{
  const float* x    = (const float*)d_in[0];
  const float* n1w  = (const float*)d_in[1];
  const float* n1b  = (const float*)d_in[2];
  const float* qkvw = (const float*)d_in[3];
  const float* qkvB = (const float*)d_in[4];
  const float* relb = (const float*)d_in[5];
  const float* pw   = (const float*)d_in[6];
  const float* pb   = (const float*)d_in[7];
  const float* n2w  = (const float*)d_in[8];
  const float* n2b  = (const float*)d_in[9];
  const float* w1   = (const float*)d_in[10];
  const float* b1   = (const float*)d_in[11];
  const float* w2   = (const float*)d_in[12];
  const float* b2   = (const float*)d_in[13];
  float* out = (float*)d_out;

  unsigned short* winb = (unsigned short*)d_ws;        // attn out [131072][128] bf16
  unsigned short* wb   = winb + 16777216;              // bf16 weights (196608 el)
  unsigned short* qkvw_b = wb;
  unsigned short* pw_b   = wb + 49152;
  unsigned short* w1_b   = wb + 65536;
  unsigned short* w2_b   = wb + 131072;
  float* be = (float*)(wb + 196608);                   // expanded bias [8][64][64] f32

  k0_cvt<<<224, 256, 0, stream>>>(qkvw, pw, w1, w2, relb, wb, be);
  k23_qkv_attn<<<2048, 256, 0, stream>>>(x, n1w, n1b, qkvw_b, qkvB, be, winb);
  k45_proj_mlp<<<2048, 256, 0, stream>>>(winb, pw_b, pb, x, n2w, n2b,
                                         w1_b, b1, w2_b, b2, out);
}

// Round 21
// 162.162 us; speedup vs baseline: 1.0606x; 1.0606x over previous
//
#include <hip/hip_runtime.h>
#include <hip/hip_bf16.h>
#include <cmath>

#define LNEPS 1e-5f

typedef __attribute__((ext_vector_type(8))) short short8v;
typedef __attribute__((ext_vector_type(4))) float f32x4;

__device__ __forceinline__ unsigned short f2bf(float f){
  unsigned u = __float_as_uint(f);
  u += 0x7fffu + ((u >> 16) & 1u);
  return (unsigned short)(u >> 16);
}
template <int P>
__device__ __forceinline__ void setprio(){
#ifdef __HIP_DEVICE_COMPILE__
  __builtin_amdgcn_s_setprio(P);
#endif
}
__device__ __forceinline__ float frcp(float x){
#ifdef __HIP_DEVICE_COMPILE__
  return __builtin_amdgcn_rcpf(x);
#else
  return 1.f / x;
#endif
}
// sigmoid-GELU: x * sigma(1.702 x). ~5 issue slots (2 on trans pipe), no LDS.
__device__ __forceinline__ float gelu_s(float x){
  return x * frcp(1.f + __expf(-1.702f * x));
}

__device__ __forceinline__ f32x4 mfma32(short8v a, short8v b, f32x4 c){
#ifdef __HIP_DEVICE_COMPILE__
  return __builtin_amdgcn_mfma_f32_16x16x32_bf16(a, b, c, 0, 0, 0);
#else
  return c;
#endif
}

// Stage 128x128 bf16 -> LDS via global_load_lds, 256 threads (8 iters).
__device__ __forceinline__ void stage128(const unsigned short* g, int ldg, short* lds){
#ifdef __HIP_DEVICE_COMPILE__
  const int t = threadIdx.x;
  const int wv = t >> 6;
  #pragma unroll
  for (int it = 0; it < 8; ++it) {
    const int flat = it * 256 + t;
    const int r = flat >> 4, c = flat & 15;
    const unsigned short* src = g + (size_t)r * ldg + ((c ^ (r & 7)) << 3);
    short* dst = lds + (size_t)(it * 256 + wv * 64) * 8;
    __builtin_amdgcn_global_load_lds(
        (const __attribute__((address_space(1))) void*)src,
        (__attribute__((address_space(3))) void*)dst, 16, 0, 0);
  }
#else
  (void)g; (void)ldg; (void)lds;
#endif
}
// Stage 64x128 bf16 (256 threads).
__device__ __forceinline__ void stage64(const unsigned short* g, short* lds){
#ifdef __HIP_DEVICE_COMPILE__
  const int t = threadIdx.x;
  const int wv = t >> 6;
  #pragma unroll
  for (int it = 0; it < 4; ++it) {
    const int flat = it * 256 + t;
    const int r = flat >> 4, c = flat & 15;
    const unsigned short* src = g + (size_t)r * 128 + ((c ^ (r & 7)) << 3);
    short* dst = lds + (size_t)(it * 256 + wv * 64) * 8;
    __builtin_amdgcn_global_load_lds(
        (const __attribute__((address_space(1))) void*)src,
        (__attribute__((address_space(3))) void*)dst, 16, 0, 0);
  }
#else
  (void)g; (void)lds;
#endif
}
// Swizzled 16B fragment read: row-major [row][128 bf16] (256B rows).
__device__ __forceinline__ short8v frag_ld(const short* lds, int row, int chunk){
  return *(const short8v*)((const char*)lds + row * 256 + ((chunk ^ (row & 7)) << 4));
}

// ---------------- K0: weights f32 -> bf16, plus bias-table expansion ----------------
__global__ __launch_bounds__(256) void k0_cvt(
    const float* __restrict__ qkvw, const float* __restrict__ pw,
    const float* __restrict__ w1, const float* __restrict__ w2,
    const float* __restrict__ table,
    unsigned short* __restrict__ dst, float* __restrict__ be)
{
  if (blockIdx.x < 192) {
    const int i = (blockIdx.x * 256 + threadIdx.x) * 4;
    const float* src; int off;
    if (i < 49152)       { src = qkvw; off = i; }
    else if (i < 65536)  { src = pw;   off = i - 49152; }
    else if (i < 131072) { src = w1;   off = i - 65536; }
    else                 { src = w2;   off = i - 131072; }
    const float4 v = *(const float4*)(src + off);
    ushort4 o = { f2bf(v.x), f2bf(v.y), f2bf(v.z), f2bf(v.w) };
    *(ushort4*)(dst + i) = o;
  } else {
    const int i = (blockIdx.x - 192) * 256 + threadIdx.x;   // 8192 float4 slots
    const int m4 = (i & 15) * 4;
    const int r  = (i >> 4) & 63;
    const int h  = i >> 10;
    const int i1 = r >> 3, j1 = r & 7;
    float o[4];
    #pragma unroll
    for (int e = 0; e < 4; ++e) {
      const int m = m4 + e;
      const int i2 = m >> 3, j2 = m & 7;
      o[e] = table[((i1 - i2 + 7) * 15 + (j1 - j2 + 7)) * 8 + h];
    }
    float4 ov = { o[0], o[1], o[2], o[3] };
    *(float4*)(be + ((h * 64 + r) * 64 + m4)) = ov;
  }
}

// ---------------- K23: fused LN1+shift+window + qkv GEMM + window attention ----------------
// One window per 256-thread block; LDS = 80 KB -> 2 blocks/CU.
__global__ __launch_bounds__(256, 2) void k23_qkv_attn(
    const float* __restrict__ x,
    const float* __restrict__ gw, const float* __restrict__ gb,
    const unsigned short* __restrict__ Wb,
    const float* __restrict__ bias,
    const float* __restrict__ be,          // expanded bias [8][64][64] f32
    unsigned short* __restrict__ attn)
{
  __shared__ __align__(16) short At[128 * 128];   // 32K: weight tile; later P (4K/wave)
  __shared__ __align__(16) short Bt[64 * 128];    // 16K: ln1(x); later V^T [8][16][64]
  __shared__ __align__(16) short QK[64 * 256];    // 32K: Q|K (512B rows, swizzled)
  const int t = threadIdx.x;
  const int win = blockIdx.x;
  const int row0 = win * 64;
  stage128(Wb, 128, At);                          // Wq tile, async under LN
  #pragma unroll
  for (int it = 0; it < 4; ++it) {
    const int flat = it * 256 + t;
    const int r = flat >> 4, c = flat & 15;
    const int row = row0 + r;
    const int wid = row >> 6, n = row & 63;
    const int b = wid >> 10, rem = wid & 1023;
    const int wh = rem >> 5, wwi = rem & 31;
    const int i2 = n >> 3, j2 = n & 7;
    const int sh = (wh * 8 + i2 + 4) & 255;
    const int sw = (wwi * 8 + j2 + 4) & 255;
    const float* src = x + (((size_t)b << 16) + sh * 256 + sw) * 128 + c * 8;
    const float4 a0 = *(const float4*)src;
    const float4 a1 = *(const float4*)(src + 4);
    float s  = a0.x + a0.y + a0.z + a0.w + a1.x + a1.y + a1.z + a1.w;
    float ss = a0.x*a0.x + a0.y*a0.y + a0.z*a0.z + a0.w*a0.w
             + a1.x*a1.x + a1.y*a1.y + a1.z*a1.z + a1.w*a1.w;
    s += __shfl_xor(s, 1); ss += __shfl_xor(ss, 1);
    s += __shfl_xor(s, 2); ss += __shfl_xor(ss, 2);
    s += __shfl_xor(s, 4); ss += __shfl_xor(ss, 4);
    s += __shfl_xor(s, 8); ss += __shfl_xor(ss, 8);
    const float mean = s * 0.0078125f;
    const float rstd = rsqrtf(ss * 0.0078125f - mean * mean + LNEPS);
    const float4 g0 = *(const float4*)(gw + c * 8), g1 = *(const float4*)(gw + c * 8 + 4);
    const float4 c0 = *(const float4*)(gb + c * 8), c1 = *(const float4*)(gb + c * 8 + 4);
    uint4 pk;
    pk.x = (unsigned)f2bf((a0.x - mean) * rstd * g0.x + c0.x)
         | ((unsigned)f2bf((a0.y - mean) * rstd * g0.y + c0.y) << 16);
    pk.y = (unsigned)f2bf((a0.z - mean) * rstd * g0.z + c0.z)
         | ((unsigned)f2bf((a0.w - mean) * rstd * g0.w + c0.w) << 16);
    pk.z = (unsigned)f2bf((a1.x - mean) * rstd * g1.x + c1.x)
         | ((unsigned)f2bf((a1.y - mean) * rstd * g1.y + c1.y) << 16);
    pk.w = (unsigned)f2bf((a1.z - mean) * rstd * g1.z + c1.z)
         | ((unsigned)f2bf((a1.w - mean) * rstd * g1.w + c1.w) << 16);
    *(uint4*)((char*)Bt + r * 256 + ((c ^ (r & 7)) << 4)) = pk;
  }
  __syncthreads();

  const int l = t & 63, w = t >> 6, w0 = w & 1, w1 = w >> 1;   // 4 waves: 2 col x 2 row
  const int g = l >> 4, rl = l & 15;
  const f32x4 z = {0.f, 0.f, 0.f, 0.f};

  for (int nt = 0; nt < 3; ++nt) {
    f32x4 acc[4][2];
    #pragma unroll
    for (int i = 0; i < 4; ++i) { acc[i][0] = z; acc[i][1] = z; }
    #pragma unroll
    for (int kk = 0; kk < 4; ++kk) {
      short8v a[4], b[2];
      #pragma unroll
      for (int i = 0; i < 4; ++i) a[i] = frag_ld(At, w0 * 64 + i * 16 + rl, kk * 4 + g);
      #pragma unroll
      for (int j = 0; j < 2; ++j) b[j] = frag_ld(Bt, w1 * 32 + j * 16 + rl, kk * 4 + g);
      #pragma unroll
      for (int i = 0; i < 4; ++i)
        #pragma unroll
        for (int j = 0; j < 2; ++j)
          acc[i][j] = mfma32(a[i], b[j], acc[i][j]);
    }
    if (nt < 2) {
      __syncthreads();                            // At reads done block-wide
      stage128(Wb + (size_t)(nt + 1) * 16384, 128, At);   // T14: issue next tile
      #pragma unroll
      for (int i = 0; i < 4; ++i) {               // QK-write covers stage latency
        const int c = w0 * 64 + i * 16 + 4 * g;
        const float4 bv = *(const float4*)(bias + nt * 128 + c);
        const int chunk = nt * 16 + (c >> 3), inner = (c & 7) * 2;
        #pragma unroll
        for (int j = 0; j < 2; ++j) {
          const int r = w1 * 32 + j * 16 + rl;
          ushort4 o = { f2bf(acc[i][j][0] + bv.x), f2bf(acc[i][j][1] + bv.y),
                        f2bf(acc[i][j][2] + bv.z), f2bf(acc[i][j][3] + bv.w) };
          *(ushort4*)((char*)QK + r * 512 + ((chunk ^ (r & 7)) << 4) + inner) = o;
        }
      }
      __syncthreads();                            // next weight tile + QK writes ready
    } else {
      __syncthreads();                            // all At/Bt reads done -> Bt reusable
      #pragma unroll
      for (int i = 0; i < 4; ++i) {
        const int c = w0 * 64 + i * 16 + 4 * g;
        const int h2 = c >> 4, db = c & 15;
        const float4 bv = *(const float4*)(bias + 256 + c);
        const float ba[4] = {bv.x, bv.y, bv.z, bv.w};
        #pragma unroll
        for (int j = 0; j < 2; ++j) {
          const int m = w1 * 32 + j * 16 + rl;    // token index in window
          char* vb = (char*)Bt + h2 * 2048;
          #pragma unroll
          for (int e = 0; e < 4; ++e) {
            const int d = db + e;
            *(unsigned short*)(vb + d * 128 + (((m >> 3) ^ (d & 7)) << 4) + (m & 7) * 2)
                = f2bf(acc[i][j][e] + ba[e]);
          }
        }
      }
      __syncthreads();                            // V^T visible
    }
  }

  // ---- attention: 4 waves x 2 heads each ----
  char* Pw = (char*)At + w * 4096;
  const short8v zz = {0,0,0,0,0,0,0,0};
  for (int hh = 0; hh < 2; ++hh) {
    const int h = w * 2 + hh;
    short8v qf[4], kf[4];
    if (g < 2) {
      #pragma unroll
      for (int rf = 0; rf < 4; ++rf) {
        const int r = rf * 16 + rl;
        qf[rf] = *(const short8v*)((char*)QK + r * 512 + (((2 * h + g) ^ (r & 7)) << 4));
      }
      #pragma unroll
      for (int mf = 0; mf < 4; ++mf) {
        const int r = mf * 16 + rl;
        kf[mf] = *(const short8v*)((char*)QK + r * 512 + (((16 + 2 * h + g) ^ (r & 7)) << 4));
      }
    } else {
      #pragma unroll
      for (int i = 0; i < 4; ++i) { qf[i] = zz; kf[i] = zz; }
    }
    f32x4 s[4][4];
    #pragma unroll
    for (int mf = 0; mf < 4; ++mf)
      #pragma unroll
      for (int rf = 0; rf < 4; ++rf)
        s[mf][rf] = mfma32(kf[mf], qf[rf], z);    // S^T: m = mf*16+4g+e, r = rf*16+rl
    float sum[4];
    #pragma unroll
    for (int rf = 0; rf < 4; ++rf) {
      const int r = rf * 16 + rl;
      const float* bp = be + (size_t)(h * 64 + r) * 64;
      float mx = -1e30f;
      #pragma unroll
      for (int mf = 0; mf < 4; ++mf) {
        const float4 bv = *(const float4*)(bp + mf * 16 + g * 4);
        const float ba[4] = {bv.x, bv.y, bv.z, bv.w};
        #pragma unroll
        for (int e = 0; e < 4; ++e) {
          const float v = s[mf][rf][e] * 0.25f + ba[e];
          s[mf][rf][e] = v;
          mx = fmaxf(mx, v);
        }
      }
      mx = fmaxf(mx, __shfl_xor(mx, 16));
      mx = fmaxf(mx, __shfl_xor(mx, 32));
      float sm = 0.f;
      #pragma unroll
      for (int mf = 0; mf < 4; ++mf)
        #pragma unroll
        for (int e = 0; e < 4; ++e) {
          const float ev = __expf(s[mf][rf][e] - mx);
          s[mf][rf][e] = ev;
          sm += ev;
        }
      sm += __shfl_xor(sm, 16);
      sm += __shfl_xor(sm, 32);
      sum[rf] = sm;
    }
    // PV in two m-halves through the per-wave P buffer (intra-wave ordering).
    const char* vbase = (char*)Bt + h * 2048;
    f32x4 o[4];
    #pragma unroll
    for (int rf = 0; rf < 4; ++rf) o[rf] = z;
    #pragma unroll
    for (int hm = 0; hm < 2; ++hm) {
      #pragma unroll
      for (int rf = 0; rf < 4; ++rf) {
        const int r = rf * 16 + rl;
        #pragma unroll
        for (int mfl = 0; mfl < 2; ++mfl) {
          const int mf = hm * 2 + mfl;
          uint2 u;
          u.x = (unsigned)f2bf(s[mf][rf][0]) | ((unsigned)f2bf(s[mf][rf][1]) << 16);
          u.y = (unsigned)f2bf(s[mf][rf][2]) | ((unsigned)f2bf(s[mf][rf][3]) << 16);
          *(uint2*)(Pw + r * 64 + (((mfl * 2 + (g >> 1)) ^ ((r >> 1) & 3)) << 4) + (g & 1) * 8) = u;
        }
      }
      const short8v va = *(const short8v*)(vbase + rl * 128 + (((hm * 4 + g) ^ (rl & 7)) << 4));
      #pragma unroll
      for (int rf = 0; rf < 4; ++rf) {
        const int r = rf * 16 + rl;
        const short8v pb = *(const short8v*)(Pw + r * 64 + ((g ^ ((r >> 1) & 3)) << 4));
        o[rf] = mfma32(va, pb, o[rf]);
      }
    }
    #pragma unroll
    for (int rf = 0; rf < 4; ++rf) {
      const float inv = 1.f / sum[rf];
      const int r = rf * 16 + rl;
      ushort4 ov = { f2bf(o[rf][0] * inv), f2bf(o[rf][1] * inv),
                     f2bf(o[rf][2] * inv), f2bf(o[rf][3] * inv) };
      *(ushort4*)(attn + ((size_t)win * 64 + r) * 128 + h * 16 + g * 4) = ov;
    }
  }
}

// ---------------- K45: fused proj + unshift-residual + LN2 + fc1 + GELU + fc2 + residual ----------------
// r21 single variable: LUT GELU -> sigmoid-GELU (x*sigma(1.702x)), Gt deleted.
__global__ __launch_bounds__(256, 2) void k45_proj_mlp(
    const unsigned short* __restrict__ A,
    const unsigned short* __restrict__ pwb,
    const float* __restrict__ pb,
    const float* __restrict__ xin,
    const float* __restrict__ gw, const float* __restrict__ gb,
    const unsigned short* __restrict__ w1b, const float* __restrict__ b1,
    const unsigned short* __restrict__ w2b, const float* __restrict__ b2,
    float* __restrict__ out)
{
  __shared__ __align__(16) short Xt[64 * 128];
  __shared__ __align__(16) short Ht[64 * 128];
  __shared__ __align__(16) short Wt[128 * 128];
  __shared__ float2 Red[64 * 8];
  const int t = threadIdx.x;
  const int row0 = blockIdx.x * 64;
  stage128(pwb, 128, Wt);
  stage64(A + (size_t)row0 * 128, Ht);
  const int l = t & 63, w = t >> 6, w0 = w & 1, w1 = w >> 1;
  const int g = l >> 4, rl = l & 15;
  size_t obase[2];
  float4 xv[4][2];
  #pragma unroll
  for (int j = 0; j < 2; ++j) {
    const int r = row0 + w1 * 32 + j * 16 + rl;
    const int wn = r >> 6, n = r & 63;
    const int b_ = wn >> 10, rem = wn & 1023;
    const int wh = rem >> 5, ww = rem & 31;
    const int si = n >> 3, sj = n & 7;
    const int hd = (wh * 8 + si + 4) & 255;
    const int wd = (ww * 8 + sj + 4) & 255;
    obase[j] = (((size_t)b_ << 16) + hd * 256 + wd) * 128;
    #pragma unroll
    for (int i = 0; i < 4; ++i)
      xv[i][j] = *(const float4*)(xin + obase[j] + w0 * 64 + i * 16 + 4 * g);
  }
  __syncthreads();
  const f32x4 z = {0.f, 0.f, 0.f, 0.f};
  f32x4 x2r[4][2];
  #pragma unroll
  for (int i = 0; i < 4; ++i) { x2r[i][0] = z; x2r[i][1] = z; }
  setprio<1>();
  #pragma unroll
  for (int kk = 0; kk < 4; ++kk) {
    short8v a[4], b[2];
    #pragma unroll
    for (int i = 0; i < 4; ++i) a[i] = frag_ld(Wt, w0 * 64 + i * 16 + rl, kk * 4 + g);
    #pragma unroll
    for (int j = 0; j < 2; ++j) b[j] = frag_ld(Ht, w1 * 32 + j * 16 + rl, kk * 4 + g);
    #pragma unroll
    for (int i = 0; i < 4; ++i)
      #pragma unroll
      for (int j = 0; j < 2; ++j)
        x2r[i][j] = mfma32(a[i], b[j], x2r[i][j]);
  }
  setprio<0>();
  #pragma unroll
  for (int i = 0; i < 4; ++i) {
    const float4 bv = *(const float4*)(pb + w0 * 64 + i * 16 + 4 * g);
    #pragma unroll
    for (int j = 0; j < 2; ++j) {
      x2r[i][j][0] += xv[i][j].x + bv.x;
      x2r[i][j][1] += xv[i][j].y + bv.y;
      x2r[i][j][2] += xv[i][j].z + bv.z;
      x2r[i][j][3] += xv[i][j].w + bv.w;
    }
  }
  #pragma unroll
  for (int j = 0; j < 2; ++j) {
    float s = 0.f, ss = 0.f;
    #pragma unroll
    for (int i = 0; i < 4; ++i)
      #pragma unroll
      for (int e = 0; e < 4; ++e) { const float v = x2r[i][j][e]; s += v; ss += v * v; }
    Red[(w1 * 32 + j * 16 + rl) * 8 + (w0 * 4 + g)] = make_float2(s, ss);
  }
  __syncthreads();                         // Red ready AND all proj Wt reads done
  stage128(w1b, 128, Wt);                  // T14: W1[0] hides under LN2 finish + Xt write
  float mean[2], rstd[2];
  #pragma unroll
  for (int j = 0; j < 2; ++j) {
    const float2* rp = &Red[(w1 * 32 + j * 16 + rl) * 8];
    float s = 0.f, ss = 0.f;
    #pragma unroll
    for (int k = 0; k < 8; ++k) { s += rp[k].x; ss += rp[k].y; }
    mean[j] = s * 0.0078125f;
    rstd[j] = rsqrtf(ss * 0.0078125f - mean[j] * mean[j] + LNEPS);
  }
  #pragma unroll
  for (int i = 0; i < 4; ++i) {
    const int c = w0 * 64 + i * 16 + 4 * g;
    const float4 g4 = *(const float4*)(gw + c);
    const float4 c4 = *(const float4*)(gb + c);
    #pragma unroll
    for (int j = 0; j < 2; ++j) {
      const int r = w1 * 32 + j * 16 + rl;
      ushort4 p;
      p.x = f2bf((x2r[i][j][0] - mean[j]) * rstd[j] * g4.x + c4.x);
      p.y = f2bf((x2r[i][j][1] - mean[j]) * rstd[j] * g4.y + c4.y);
      p.z = f2bf((x2r[i][j][2] - mean[j]) * rstd[j] * g4.z + c4.z);
      p.w = f2bf((x2r[i][j][3] - mean[j]) * rstd[j] * g4.w + c4.w);
      const int chunk = c >> 3, inner = (c & 7) * 2;
      *(ushort4*)((char*)Xt + r * 256 + ((chunk ^ (r & 7)) << 4) + inner) = p;
    }
  }
  f32x4 oacc[4][2];
  #pragma unroll
  for (int i = 0; i < 4; ++i) { oacc[i][0] = z; oacc[i][1] = z; }
  for (int sb = 0; sb < 4; ++sb) {
    __syncthreads();                       // sb=0: Xt + W1[0] ready; sb>0: prev Wt/Ht reads done
    if (sb > 0) {
      stage128(w1b + (size_t)sb * 16384, 128, Wt);
      __syncthreads();                     // W1[sb] ready
    }
    f32x4 hacc[4][2];
    #pragma unroll
    for (int i = 0; i < 4; ++i) { hacc[i][0] = z; hacc[i][1] = z; }
    setprio<1>();
    #pragma unroll
    for (int kk = 0; kk < 4; ++kk) {
      short8v a[4], b[2];
      #pragma unroll
      for (int i = 0; i < 4; ++i) a[i] = frag_ld(Wt, w0 * 64 + i * 16 + rl, kk * 4 + g);
      #pragma unroll
      for (int j = 0; j < 2; ++j) b[j] = frag_ld(Xt, w1 * 32 + j * 16 + rl, kk * 4 + g);
      #pragma unroll
      for (int i = 0; i < 4; ++i)
        #pragma unroll
        for (int j = 0; j < 2; ++j)
          hacc[i][j] = mfma32(a[i], b[j], hacc[i][j]);
    }
    setprio<0>();
    __syncthreads();                       // fc1 done reading Wt
    stage128(w2b + (size_t)sb * 128, 512, Wt);   // T14: W2 issued BEFORE GELU
    #pragma unroll
    for (int i = 0; i < 4; ++i) {
      const int cl = w0 * 64 + i * 16 + 4 * g;
      const float4 b1v = *(const float4*)(b1 + sb * 128 + cl);
      const float ba[4] = {b1v.x, b1v.y, b1v.z, b1v.w};
      #pragma unroll
      for (int j = 0; j < 2; ++j) {
        const int r = w1 * 32 + j * 16 + rl;
        ushort4 p;
        p.x = f2bf(gelu_s(hacc[i][j][0] + ba[0]));
        p.y = f2bf(gelu_s(hacc[i][j][1] + ba[1]));
        p.z = f2bf(gelu_s(hacc[i][j][2] + ba[2]));
        p.w = f2bf(gelu_s(hacc[i][j][3] + ba[3]));
        const int chunk = cl >> 3, inner = (cl & 7) * 2;
        *(ushort4*)((char*)Ht + r * 256 + ((chunk ^ (r & 7)) << 4) + inner) = p;
      }
    }
    __syncthreads();                       // W2 + Ht ready
    setprio<1>();
    #pragma unroll
    for (int kk = 0; kk < 4; ++kk) {
      short8v a[4], b[2];
      #pragma unroll
      for (int i = 0; i < 4; ++i) a[i] = frag_ld(Wt, w0 * 64 + i * 16 + rl, kk * 4 + g);
      #pragma unroll
      for (int j = 0; j < 2; ++j) b[j] = frag_ld(Ht, w1 * 32 + j * 16 + rl, kk * 4 + g);
      #pragma unroll
      for (int i = 0; i < 4; ++i)
        #pragma unroll
        for (int j = 0; j < 2; ++j)
          oacc[i][j] = mfma32(a[i], b[j], oacc[i][j]);
    }
    setprio<0>();
  }
  #pragma unroll
  for (int i = 0; i < 4; ++i) {
    const int c = w0 * 64 + i * 16 + 4 * g;
    const float4 bv = *(const float4*)(b2 + c);
    #pragma unroll
    for (int j = 0; j < 2; ++j) {
      float4 o = { x2r[i][j][0] + oacc[i][j][0] + bv.x,
                   x2r[i][j][1] + oacc[i][j][1] + bv.y,
                   x2r[i][j][2] + oacc[i][j][2] + bv.z,
                   x2r[i][j][3] + oacc[i][j][3] + bv.w };
      *(float4*)(out + obase[j] + c) = o;
    }
  }
}

extern "C" void kernel_launch(void* const* d_in, const int* in_sizes, int n_in,
                              void* d_out, int out_size, void* d_ws, size_t ws_size,
                              hipStream_t stream)
{
  const float* x    = (const float*)d_in[0];
  const float* n1w  = (const float*)d_in[1];
  const float* n1b  = (const float*)d_in[2];
  const float* qkvw = (const float*)d_in[3];
  const float* qkvB = (const float*)d_in[4];
  const float* relb = (const float*)d_in[5];
  const float* pw   = (const float*)d_in[6];
  const float* pb   = (const float*)d_in[7];
  const float* n2w  = (const float*)d_in[8];
  const float* n2b  = (const float*)d_in[9];
  const float* w1   = (const float*)d_in[10];
  const float* b1   = (const float*)d_in[11];
  const float* w2   = (const float*)d_in[12];
  const float* b2   = (const float*)d_in[13];
  float* out = (float*)d_out;

  unsigned short* winb = (unsigned short*)d_ws;        // attn out [131072][128] bf16
  unsigned short* wb   = winb + 16777216;              // bf16 weights (196608 el)
  unsigned short* qkvw_b = wb;
  unsigned short* pw_b   = wb + 49152;
  unsigned short* w1_b   = wb + 65536;
  unsigned short* w2_b   = wb + 131072;
  float* be = (float*)(wb + 196608);                   // expanded bias [8][64][64] f32

  k0_cvt<<<224, 256, 0, stream>>>(qkvw, pw, w1, w2, relb, wb, be);
  k23_qkv_attn<<<2048, 256, 0, stream>>>(x, n1w, n1b, qkvw_b, qkvB, be, winb);
  k45_proj_mlp<<<2048, 256, 0, stream>>>(winb, pw_b, pb, x, n2w, n2b,
                                         w1_b, b1, w2_b, b2, out);
}

// Round 22
// 150.293 us; speedup vs baseline: 1.1443x; 1.0790x over previous
//
#include <hip/hip_runtime.h>
#include <hip/hip_bf16.h>
#include <cmath>

#define LNEPS 1e-5f

typedef __attribute__((ext_vector_type(8))) short short8v;
typedef __attribute__((ext_vector_type(4))) float f32x4;

__device__ __forceinline__ unsigned short f2bf(float f){
  unsigned u = __float_as_uint(f);
  u += 0x7fffu + ((u >> 16) & 1u);
  return (unsigned short)(u >> 16);
}
template <int P>
__device__ __forceinline__ void setprio(){
#ifdef __HIP_DEVICE_COMPILE__
  __builtin_amdgcn_s_setprio(P);
#endif
}
__device__ __forceinline__ float frcp(float x){
#ifdef __HIP_DEVICE_COMPILE__
  return __builtin_amdgcn_rcpf(x);
#else
  return 1.f / x;
#endif
}
// sigmoid-GELU: x * sigma(1.702 x). ~5 issue slots (2 on trans pipe), no LDS.
__device__ __forceinline__ float gelu_s(float x){
  return x * frcp(1.f + __expf(-1.702f * x));
}

__device__ __forceinline__ f32x4 mfma32(short8v a, short8v b, f32x4 c){
#ifdef __HIP_DEVICE_COMPILE__
  return __builtin_amdgcn_mfma_f32_16x16x32_bf16(a, b, c, 0, 0, 0);
#else
  return c;
#endif
}

// Stage 128x128 bf16 -> LDS via global_load_lds, 256 threads (8 iters).
__device__ __forceinline__ void stage128(const unsigned short* g, int ldg, short* lds){
#ifdef __HIP_DEVICE_COMPILE__
  const int t = threadIdx.x;
  const int wv = t >> 6;
  #pragma unroll
  for (int it = 0; it < 8; ++it) {
    const int flat = it * 256 + t;
    const int r = flat >> 4, c = flat & 15;
    const unsigned short* src = g + (size_t)r * ldg + ((c ^ (r & 7)) << 3);
    short* dst = lds + (size_t)(it * 256 + wv * 64) * 8;
    __builtin_amdgcn_global_load_lds(
        (const __attribute__((address_space(1))) void*)src,
        (__attribute__((address_space(3))) void*)dst, 16, 0, 0);
  }
#else
  (void)g; (void)ldg; (void)lds;
#endif
}
// Swizzled 16B fragment read: row-major [row][128 bf16] (256B rows).
__device__ __forceinline__ short8v frag_ld(const short* lds, int row, int chunk){
  return *(const short8v*)((const char*)lds + row * 256 + ((chunk ^ (row & 7)) << 4));
}

// ---------------- K0: weights f32 -> bf16, plus bias-table expansion ----------------
__global__ __launch_bounds__(256) void k0_cvt(
    const float* __restrict__ qkvw, const float* __restrict__ pw,
    const float* __restrict__ w1, const float* __restrict__ w2,
    const float* __restrict__ table,
    unsigned short* __restrict__ dst, float* __restrict__ be)
{
  if (blockIdx.x < 192) {
    const int i = (blockIdx.x * 256 + threadIdx.x) * 4;
    const float* src; int off;
    if (i < 49152)       { src = qkvw; off = i; }
    else if (i < 65536)  { src = pw;   off = i - 49152; }
    else if (i < 131072) { src = w1;   off = i - 65536; }
    else                 { src = w2;   off = i - 131072; }
    const float4 v = *(const float4*)(src + off);
    ushort4 o = { f2bf(v.x), f2bf(v.y), f2bf(v.z), f2bf(v.w) };
    *(ushort4*)(dst + i) = o;
  } else {
    const int i = (blockIdx.x - 192) * 256 + threadIdx.x;   // 8192 float4 slots
    const int m4 = (i & 15) * 4;
    const int r  = (i >> 4) & 63;
    const int h  = i >> 10;
    const int i1 = r >> 3, j1 = r & 7;
    float o[4];
    #pragma unroll
    for (int e = 0; e < 4; ++e) {
      const int m = m4 + e;
      const int i2 = m >> 3, j2 = m & 7;
      o[e] = table[((i1 - i2 + 7) * 15 + (j1 - j2 + 7)) * 8 + h];
    }
    float4 ov = { o[0], o[1], o[2], o[3] };
    *(float4*)(be + ((h * 64 + r) * 64 + m4)) = ov;
  }
}

// ---------------- K2345: whole block per 64-row window tile, LDS time-shared (80 KB) ----------------
// Phase A (k23): LN1+shift+window -> qkv GEMM -> window attention (O kept in regs).
// Phase B (k45): proj + unshift-residual + LN2 + fc1 + sigmoid-GELU + fc2 + residual.
__global__ __launch_bounds__(256, 2) void k2345(
    const float* __restrict__ x,
    const float* __restrict__ g1w, const float* __restrict__ g1b,
    const unsigned short* __restrict__ qkvWb, const float* __restrict__ qkvB,
    const float* __restrict__ be,
    const unsigned short* __restrict__ pwb, const float* __restrict__ pb,
    const float* __restrict__ g2w, const float* __restrict__ g2b,
    const unsigned short* __restrict__ w1b, const float* __restrict__ b1,
    const unsigned short* __restrict__ w2b, const float* __restrict__ b2,
    float* __restrict__ out)
{
  __shared__ __align__(16) char LP[81920];
  short* At = (short*)LP;              // 32K: qkvW tile / P / projW / W1 / W2 (Wt)
  short* Bt = (short*)(LP + 32768);    // 16K: ln1(x) / V^T / Xt
  short* QK = (short*)(LP + 49152);    // 32K: Q|K ; first 16K later Ht
  float2* Red = (float2*)(LP + 65536); // 4K LN2 partials (QK 2nd half, free in phase B)
  const int t = threadIdx.x;
  const int win = blockIdx.x;
  const int row0 = win * 64;
  stage128(qkvWb, 128, At);                       // Wq tile, async under LN
  // ---- LN1 + shift + window partition -> Bt (16 threads/row, 64 rows) ----
  #pragma unroll
  for (int it = 0; it < 4; ++it) {
    const int flat = it * 256 + t;
    const int r = flat >> 4, c = flat & 15;
    const int row = row0 + r;
    const int wid = row >> 6, n = row & 63;
    const int b = wid >> 10, rem = wid & 1023;
    const int wh = rem >> 5, wwi = rem & 31;
    const int i2 = n >> 3, j2 = n & 7;
    const int sh = (wh * 8 + i2 + 4) & 255;
    const int sw = (wwi * 8 + j2 + 4) & 255;
    const float* src = x + (((size_t)b << 16) + sh * 256 + sw) * 128 + c * 8;
    const float4 a0 = *(const float4*)src;
    const float4 a1 = *(const float4*)(src + 4);
    float s  = a0.x + a0.y + a0.z + a0.w + a1.x + a1.y + a1.z + a1.w;
    float ss = a0.x*a0.x + a0.y*a0.y + a0.z*a0.z + a0.w*a0.w
             + a1.x*a1.x + a1.y*a1.y + a1.z*a1.z + a1.w*a1.w;
    s += __shfl_xor(s, 1); ss += __shfl_xor(ss, 1);
    s += __shfl_xor(s, 2); ss += __shfl_xor(ss, 2);
    s += __shfl_xor(s, 4); ss += __shfl_xor(ss, 4);
    s += __shfl_xor(s, 8); ss += __shfl_xor(ss, 8);
    const float mean = s * 0.0078125f;
    const float rstd = rsqrtf(ss * 0.0078125f - mean * mean + LNEPS);
    const float4 g0 = *(const float4*)(g1w + c * 8), g1 = *(const float4*)(g1w + c * 8 + 4);
    const float4 c0 = *(const float4*)(g1b + c * 8), c1 = *(const float4*)(g1b + c * 8 + 4);
    uint4 pk;
    pk.x = (unsigned)f2bf((a0.x - mean) * rstd * g0.x + c0.x)
         | ((unsigned)f2bf((a0.y - mean) * rstd * g0.y + c0.y) << 16);
    pk.y = (unsigned)f2bf((a0.z - mean) * rstd * g0.z + c0.z)
         | ((unsigned)f2bf((a0.w - mean) * rstd * g0.w + c0.w) << 16);
    pk.z = (unsigned)f2bf((a1.x - mean) * rstd * g1.x + c1.x)
         | ((unsigned)f2bf((a1.y - mean) * rstd * g1.y + c1.y) << 16);
    pk.w = (unsigned)f2bf((a1.z - mean) * rstd * g1.z + c1.z)
         | ((unsigned)f2bf((a1.w - mean) * rstd * g1.w + c1.w) << 16);
    *(uint4*)((char*)Bt + r * 256 + ((c ^ (r & 7)) << 4)) = pk;
  }
  __syncthreads();

  const int l = t & 63, w = t >> 6, w0 = w & 1, w1 = w >> 1;   // 4 waves: 2 col x 2 row
  const int g = l >> 4, rl = l & 15;
  const f32x4 z = {0.f, 0.f, 0.f, 0.f};

  // ---- qkv GEMM: Q|K -> QK, V -> V^T in Bt ----
  for (int nt = 0; nt < 3; ++nt) {
    f32x4 acc[4][2];
    #pragma unroll
    for (int i = 0; i < 4; ++i) { acc[i][0] = z; acc[i][1] = z; }
    #pragma unroll
    for (int kk = 0; kk < 4; ++kk) {
      short8v a[4], b[2];
      #pragma unroll
      for (int i = 0; i < 4; ++i) a[i] = frag_ld(At, w0 * 64 + i * 16 + rl, kk * 4 + g);
      #pragma unroll
      for (int j = 0; j < 2; ++j) b[j] = frag_ld(Bt, w1 * 32 + j * 16 + rl, kk * 4 + g);
      #pragma unroll
      for (int i = 0; i < 4; ++i)
        #pragma unroll
        for (int j = 0; j < 2; ++j)
          acc[i][j] = mfma32(a[i], b[j], acc[i][j]);
    }
    if (nt < 2) {
      __syncthreads();                            // At reads done block-wide
      stage128(qkvWb + (size_t)(nt + 1) * 16384, 128, At);   // T14: issue next tile
      #pragma unroll
      for (int i = 0; i < 4; ++i) {               // QK-write covers stage latency
        const int c = w0 * 64 + i * 16 + 4 * g;
        const float4 bv = *(const float4*)(qkvB + nt * 128 + c);
        const int chunk = nt * 16 + (c >> 3), inner = (c & 7) * 2;
        #pragma unroll
        for (int j = 0; j < 2; ++j) {
          const int r = w1 * 32 + j * 16 + rl;
          ushort4 o = { f2bf(acc[i][j][0] + bv.x), f2bf(acc[i][j][1] + bv.y),
                        f2bf(acc[i][j][2] + bv.z), f2bf(acc[i][j][3] + bv.w) };
          *(ushort4*)((char*)QK + r * 512 + ((chunk ^ (r & 7)) << 4) + inner) = o;
        }
      }
      __syncthreads();                            // next weight tile + QK writes ready
    } else {
      __syncthreads();                            // all At/Bt reads done -> Bt reusable
      #pragma unroll
      for (int i = 0; i < 4; ++i) {
        const int c = w0 * 64 + i * 16 + 4 * g;
        const int h2 = c >> 4, db = c & 15;
        const float4 bv = *(const float4*)(qkvB + 256 + c);
        const float ba[4] = {bv.x, bv.y, bv.z, bv.w};
        #pragma unroll
        for (int j = 0; j < 2; ++j) {
          const int m = w1 * 32 + j * 16 + rl;    // token index in window
          char* vb = (char*)Bt + h2 * 2048;
          #pragma unroll
          for (int e = 0; e < 4; ++e) {
            const int d = db + e;
            *(unsigned short*)(vb + d * 128 + (((m >> 3) ^ (d & 7)) << 4) + (m & 7) * 2)
                = f2bf(acc[i][j][e] + ba[e]);
          }
        }
      }
      __syncthreads();                            // V^T visible
    }
  }

  // ---- attention: 4 waves x 2 heads each; O kept normalized in regs ----
  char* Pw = (char*)At + w * 4096;
  const short8v zz = {0,0,0,0,0,0,0,0};
  f32x4 o2[2][4];
  for (int hh = 0; hh < 2; ++hh) {
    const int h = w * 2 + hh;
    short8v qf[4], kf[4];
    if (g < 2) {
      #pragma unroll
      for (int rf = 0; rf < 4; ++rf) {
        const int r = rf * 16 + rl;
        qf[rf] = *(const short8v*)((char*)QK + r * 512 + (((2 * h + g) ^ (r & 7)) << 4));
      }
      #pragma unroll
      for (int mf = 0; mf < 4; ++mf) {
        const int r = mf * 16 + rl;
        kf[mf] = *(const short8v*)((char*)QK + r * 512 + (((16 + 2 * h + g) ^ (r & 7)) << 4));
      }
    } else {
      #pragma unroll
      for (int i = 0; i < 4; ++i) { qf[i] = zz; kf[i] = zz; }
    }
    f32x4 s[4][4];
    #pragma unroll
    for (int mf = 0; mf < 4; ++mf)
      #pragma unroll
      for (int rf = 0; rf < 4; ++rf)
        s[mf][rf] = mfma32(kf[mf], qf[rf], z);    // S^T: m = mf*16+4g+e, r = rf*16+rl
    float sum[4];
    #pragma unroll
    for (int rf = 0; rf < 4; ++rf) {
      const int r = rf * 16 + rl;
      const float* bp = be + (size_t)(h * 64 + r) * 64;
      float mx = -1e30f;
      #pragma unroll
      for (int mf = 0; mf < 4; ++mf) {
        const float4 bv = *(const float4*)(bp + mf * 16 + g * 4);
        const float ba[4] = {bv.x, bv.y, bv.z, bv.w};
        #pragma unroll
        for (int e = 0; e < 4; ++e) {
          const float v = s[mf][rf][e] * 0.25f + ba[e];
          s[mf][rf][e] = v;
          mx = fmaxf(mx, v);
        }
      }
      mx = fmaxf(mx, __shfl_xor(mx, 16));
      mx = fmaxf(mx, __shfl_xor(mx, 32));
      float sm = 0.f;
      #pragma unroll
      for (int mf = 0; mf < 4; ++mf)
        #pragma unroll
        for (int e = 0; e < 4; ++e) {
          const float ev = __expf(s[mf][rf][e] - mx);
          s[mf][rf][e] = ev;
          sm += ev;
        }
      sm += __shfl_xor(sm, 16);
      sm += __shfl_xor(sm, 32);
      sum[rf] = sm;
    }
    // PV in two m-halves through the per-wave P buffer (intra-wave ordering).
    const char* vbase = (char*)Bt + h * 2048;
    f32x4 o[4];
    #pragma unroll
    for (int rf = 0; rf < 4; ++rf) o[rf] = z;
    #pragma unroll
    for (int hm = 0; hm < 2; ++hm) {
      #pragma unroll
      for (int rf = 0; rf < 4; ++rf) {
        const int r = rf * 16 + rl;
        #pragma unroll
        for (int mfl = 0; mfl < 2; ++mfl) {
          const int mf = hm * 2 + mfl;
          uint2 u;
          u.x = (unsigned)f2bf(s[mf][rf][0]) | ((unsigned)f2bf(s[mf][rf][1]) << 16);
          u.y = (unsigned)f2bf(s[mf][rf][2]) | ((unsigned)f2bf(s[mf][rf][3]) << 16);
          *(uint2*)(Pw + r * 64 + (((mfl * 2 + (g >> 1)) ^ ((r >> 1) & 3)) << 4) + (g & 1) * 8) = u;
        }
      }
      const short8v va = *(const short8v*)(vbase + rl * 128 + (((hm * 4 + g) ^ (rl & 7)) << 4));
      #pragma unroll
      for (int rf = 0; rf < 4; ++rf) {
        const int r = rf * 16 + rl;
        const short8v pbv = *(const short8v*)(Pw + r * 64 + ((g ^ ((r >> 1) & 3)) << 4));
        o[rf] = mfma32(va, pbv, o[rf]);
      }
    }
    #pragma unroll
    for (int rf = 0; rf < 4; ++rf) {
      const float inv = 1.f / sum[rf];
      o2[hh][rf][0] = o[rf][0] * inv; o2[hh][rf][1] = o[rf][1] * inv;
      o2[hh][rf][2] = o[rf][2] * inv; o2[hh][rf][3] = o[rf][3] * inv;
    }
  }

  // ---- phase transition: attn(regs) -> Ht (QK space); projW -> At; x residual loads ----
  __syncthreads();                                // all QK/Bt/At(P) reads done
  stage128(pwb, 128, At);                         // projW async under the writes below
  short* Ht = QK;                                 // first 16K of QK
  #pragma unroll
  for (int hh = 0; hh < 2; ++hh) {
    const int h = w * 2 + hh;
    const int chunk = h * 2 + (g >> 1), inner = (g & 1) * 8;
    #pragma unroll
    for (int rf = 0; rf < 4; ++rf) {
      const int r = rf * 16 + rl;
      ushort4 ov = { f2bf(o2[hh][rf][0]), f2bf(o2[hh][rf][1]),
                     f2bf(o2[hh][rf][2]), f2bf(o2[hh][rf][3]) };
      *(ushort4*)((char*)Ht + r * 256 + ((chunk ^ (r & 7)) << 4) + inner) = ov;
    }
  }
  size_t obase[2];
  float4 xv[4][2];
  #pragma unroll
  for (int j = 0; j < 2; ++j) {
    const int r = row0 + w1 * 32 + j * 16 + rl;
    const int wn = r >> 6, n = r & 63;
    const int b_ = wn >> 10, rem = wn & 1023;
    const int wh = rem >> 5, ww = rem & 31;
    const int si = n >> 3, sj = n & 7;
    const int hd = (wh * 8 + si + 4) & 255;
    const int wd = (ww * 8 + sj + 4) & 255;
    obase[j] = (((size_t)b_ << 16) + hd * 256 + wd) * 128;
    #pragma unroll
    for (int i = 0; i < 4; ++i)
      xv[i][j] = *(const float4*)(x + obase[j] + w0 * 64 + i * 16 + 4 * g);
  }
  __syncthreads();                                // projW (At) + Ht ready

  // ---- proj MFMA ----
  f32x4 x2r[4][2];
  #pragma unroll
  for (int i = 0; i < 4; ++i) { x2r[i][0] = z; x2r[i][1] = z; }
  setprio<1>();
  #pragma unroll
  for (int kk = 0; kk < 4; ++kk) {
    short8v a[4], b[2];
    #pragma unroll
    for (int i = 0; i < 4; ++i) a[i] = frag_ld(At, w0 * 64 + i * 16 + rl, kk * 4 + g);
    #pragma unroll
    for (int j = 0; j < 2; ++j) b[j] = frag_ld(Ht, w1 * 32 + j * 16 + rl, kk * 4 + g);
    #pragma unroll
    for (int i = 0; i < 4; ++i)
      #pragma unroll
      for (int j = 0; j < 2; ++j)
        x2r[i][j] = mfma32(a[i], b[j], x2r[i][j]);
  }
  setprio<0>();
  #pragma unroll
  for (int i = 0; i < 4; ++i) {
    const float4 bv = *(const float4*)(pb + w0 * 64 + i * 16 + 4 * g);
    #pragma unroll
    for (int j = 0; j < 2; ++j) {
      x2r[i][j][0] += xv[i][j].x + bv.x;
      x2r[i][j][1] += xv[i][j].y + bv.y;
      x2r[i][j][2] += xv[i][j].z + bv.z;
      x2r[i][j][3] += xv[i][j].w + bv.w;
    }
  }
  #pragma unroll
  for (int j = 0; j < 2; ++j) {
    float s = 0.f, ss = 0.f;
    #pragma unroll
    for (int i = 0; i < 4; ++i)
      #pragma unroll
      for (int e = 0; e < 4; ++e) { const float v = x2r[i][j][e]; s += v; ss += v * v; }
    Red[(w1 * 32 + j * 16 + rl) * 8 + (w0 * 4 + g)] = make_float2(s, ss);
  }
  __syncthreads();                         // Red ready AND all proj At reads done
  stage128(w1b, 128, At);                  // T14: W1[0] hides under LN2 finish + Xt write
  float mean[2], rstd[2];
  #pragma unroll
  for (int j = 0; j < 2; ++j) {
    const float2* rp = &Red[(w1 * 32 + j * 16 + rl) * 8];
    float s = 0.f, ss = 0.f;
    #pragma unroll
    for (int k = 0; k < 8; ++k) { s += rp[k].x; ss += rp[k].y; }
    mean[j] = s * 0.0078125f;
    rstd[j] = rsqrtf(ss * 0.0078125f - mean[j] * mean[j] + LNEPS);
  }
  #pragma unroll
  for (int i = 0; i < 4; ++i) {
    const int c = w0 * 64 + i * 16 + 4 * g;
    const float4 g4 = *(const float4*)(g2w + c);
    const float4 c4 = *(const float4*)(g2b + c);
    #pragma unroll
    for (int j = 0; j < 2; ++j) {
      const int r = w1 * 32 + j * 16 + rl;
      ushort4 p;
      p.x = f2bf((x2r[i][j][0] - mean[j]) * rstd[j] * g4.x + c4.x);
      p.y = f2bf((x2r[i][j][1] - mean[j]) * rstd[j] * g4.y + c4.y);
      p.z = f2bf((x2r[i][j][2] - mean[j]) * rstd[j] * g4.z + c4.z);
      p.w = f2bf((x2r[i][j][3] - mean[j]) * rstd[j] * g4.w + c4.w);
      const int chunk = c >> 3, inner = (c & 7) * 2;
      *(ushort4*)((char*)Bt + r * 256 + ((chunk ^ (r & 7)) << 4) + inner) = p;
    }
  }
  // ---- MLP: 4 phases; Xt = Bt space, Wt = At space, Ht = QK space ----
  f32x4 oacc[4][2];
  #pragma unroll
  for (int i = 0; i < 4; ++i) { oacc[i][0] = z; oacc[i][1] = z; }
  for (int sb = 0; sb < 4; ++sb) {
    __syncthreads();                       // sb=0: Xt + W1[0] ready; sb>0: prev reads done
    if (sb > 0) {
      stage128(w1b + (size_t)sb * 16384, 128, At);
      __syncthreads();                     // W1[sb] ready
    }
    f32x4 hacc[4][2];
    #pragma unroll
    for (int i = 0; i < 4; ++i) { hacc[i][0] = z; hacc[i][1] = z; }
    setprio<1>();
    #pragma unroll
    for (int kk = 0; kk < 4; ++kk) {
      short8v a[4], b[2];
      #pragma unroll
      for (int i = 0; i < 4; ++i) a[i] = frag_ld(At, w0 * 64 + i * 16 + rl, kk * 4 + g);
      #pragma unroll
      for (int j = 0; j < 2; ++j) b[j] = frag_ld(Bt, w1 * 32 + j * 16 + rl, kk * 4 + g);
      #pragma unroll
      for (int i = 0; i < 4; ++i)
        #pragma unroll
        for (int j = 0; j < 2; ++j)
          hacc[i][j] = mfma32(a[i], b[j], hacc[i][j]);
    }
    setprio<0>();
    __syncthreads();                       // fc1 done reading At
    stage128(w2b + (size_t)sb * 128, 512, At);   // T14: W2 issued BEFORE GELU
    #pragma unroll
    for (int i = 0; i < 4; ++i) {
      const int cl = w0 * 64 + i * 16 + 4 * g;
      const float4 b1v = *(const float4*)(b1 + sb * 128 + cl);
      const float ba[4] = {b1v.x, b1v.y, b1v.z, b1v.w};
      #pragma unroll
      for (int j = 0; j < 2; ++j) {
        const int r = w1 * 32 + j * 16 + rl;
        ushort4 p;
        p.x = f2bf(gelu_s(hacc[i][j][0] + ba[0]));
        p.y = f2bf(gelu_s(hacc[i][j][1] + ba[1]));
        p.z = f2bf(gelu_s(hacc[i][j][2] + ba[2]));
        p.w = f2bf(gelu_s(hacc[i][j][3] + ba[3]));
        const int chunk = cl >> 3, inner = (cl & 7) * 2;
        *(ushort4*)((char*)Ht + r * 256 + ((chunk ^ (r & 7)) << 4) + inner) = p;
      }
    }
    __syncthreads();                       // W2 + Ht ready
    setprio<1>();
    #pragma unroll
    for (int kk = 0; kk < 4; ++kk) {
      short8v a[4], b[2];
      #pragma unroll
      for (int i = 0; i < 4; ++i) a[i] = frag_ld(At, w0 * 64 + i * 16 + rl, kk * 4 + g);
      #pragma unroll
      for (int j = 0; j < 2; ++j) b[j] = frag_ld(Ht, w1 * 32 + j * 16 + rl, kk * 4 + g);
      #pragma unroll
      for (int i = 0; i < 4; ++i)
        #pragma unroll
        for (int j = 0; j < 2; ++j)
          oacc[i][j] = mfma32(a[i], b[j], oacc[i][j]);
    }
    setprio<0>();
  }
  #pragma unroll
  for (int i = 0; i < 4; ++i) {
    const int c = w0 * 64 + i * 16 + 4 * g;
    const float4 bv = *(const float4*)(b2 + c);
    #pragma unroll
    for (int j = 0; j < 2; ++j) {
      float4 o = { x2r[i][j][0] + oacc[i][j][0] + bv.x,
                   x2r[i][j][1] + oacc[i][j][1] + bv.y,
                   x2r[i][j][2] + oacc[i][j][2] + bv.z,
                   x2r[i][j][3] + oacc[i][j][3] + bv.w };
      *(float4*)(out + obase[j] + c) = o;
    }
  }
}

extern "C" void kernel_launch(void* const* d_in, const int* in_sizes, int n_in,
                              void* d_out, int out_size, void* d_ws, size_t ws_size,
                              hipStream_t stream)
{
  const float* x    = (const float*)d_in[0];
  const float* n1w  = (const float*)d_in[1];
  const float* n1b  = (const float*)d_in[2];
  const float* qkvw = (const float*)d_in[3];
  const float* qkvB = (const float*)d_in[4];
  const float* relb = (const float*)d_in[5];
  const float* pw   = (const float*)d_in[6];
  const float* pb   = (const float*)d_in[7];
  const float* n2w  = (const float*)d_in[8];
  const float* n2b  = (const float*)d_in[9];
  const float* w1   = (const float*)d_in[10];
  const float* b1   = (const float*)d_in[11];
  const float* w2   = (const float*)d_in[12];
  const float* b2   = (const float*)d_in[13];
  float* out = (float*)d_out;

  unsigned short* wb = (unsigned short*)d_ws;          // bf16 weights (196608 el)
  unsigned short* qkvw_b = wb;
  unsigned short* pw_b   = wb + 49152;
  unsigned short* w1_b   = wb + 65536;
  unsigned short* w2_b   = wb + 131072;
  float* be = (float*)(wb + 196608);                   // expanded bias [8][64][64] f32

  k0_cvt<<<224, 256, 0, stream>>>(qkvw, pw, w1, w2, relb, wb, be);
  k2345<<<2048, 256, 0, stream>>>(x, n1w, n1b, qkvw_b, qkvB, be,
                                  pw_b, pb, n2w, n2b, w1_b, b1, w2_b, b2, out);
}